// Round 10
// baseline (265.517 us; speedup 1.0000x reference)
//
#include <hip/hip_runtime.h>
#include <hip/hip_bf16.h>
#include <cmath>

// Problem constants (from reference)
#define N_TOK 32768
#define KDIM  1024
#define ODIM  1024

// GEMM tile: 128x128 block, BK=32, 8 waves duty-split:
//   waves 0-3: mean GEMM (A = x bf16), waves 4-7: var GEMM (A = x^2 bf16)
// PRE=2: x AND x^2 pre-converted in ws -> all-DMA staging, zero k-loop VALU
//        for conversion/squaring. LDS dbuf 2 x 32KB = 64KB -> 2 blocks/CU.
// PRE=1: x pre-converted; var waves sqr8 in-register (R9 path).
// PRE=0: in-kernel convert fallback.
// REGISTER LAW (R7): per-SIMD VGPR pool = 512/wave at 4 waves/SIMD;
// acc = 64 AGPR -> VGPR must stay <= 64 for 2 resident blocks.
// __launch_bounds__(512,4) forces combined <= 128.
// PAIRED-ROW LDS LAYOUT (R8): [128][32] tile as 64 LDS rows x 128B;
// matrix row r -> LDS row r>>1, slot ((r&1)<<2|kchunk) ^ (ldsrow&7). 0 conflicts (R9).
#define BM 128
#define BN 128
#define BK 32
#define NKT (KDIM / BK)   // 32 k-tiles
#define THREADS 512

typedef float          f32x4  __attribute__((ext_vector_type(4)));
typedef __bf16         bf16x8 __attribute__((ext_vector_type(8)));
typedef unsigned short us8    __attribute__((ext_vector_type(8)));
typedef unsigned short us2    __attribute__((ext_vector_type(2)));

// round-to-nearest-even f32 -> bf16
static __device__ __forceinline__ unsigned short f2bf(float f) {
  unsigned u = __builtin_bit_cast(unsigned, f);
  u += 0x7FFFu + ((u >> 16) & 1u);
  return (unsigned short)(u >> 16);
}
static __device__ __forceinline__ unsigned short bfc(float f) {
  return __builtin_bit_cast(unsigned short, (__bf16)f);
}
static __device__ __forceinline__ float bf2f(unsigned short u) {
  return __builtin_bit_cast(float, (unsigned)u << 16);
}

static __device__ __forceinline__ f32x4 mfma16(us8 a, us8 b, f32x4 c) {
  return __builtin_amdgcn_mfma_f32_16x16x32_bf16(
      __builtin_bit_cast(bf16x8, a), __builtin_bit_cast(bf16x8, b), c, 0, 0, 0);
}

static __device__ __forceinline__ void gl_lds16(const void* g, void* l) {
  __builtin_amdgcn_global_load_lds(
      (const __attribute__((address_space(1))) void*)g,
      (__attribute__((address_space(3))) void*)l, 16, 0, 0);
}

// elementwise square of 8 bf16 — PRE<=1 fallback only
static __device__ __forceinline__ us8 sqr8(us8 a) {
  us8 r;
#pragma unroll
  for (int i = 0; i < 8; ++i) {
    float f = bf2f(a[i]);
    r[i] = bfc(f * f);
  }
  return r;
}

// ---------------------------------------------------------------------------
// Prep 1: weight_logits [O][I][2] -> bf16 W_mean, W_var
// ---------------------------------------------------------------------------
__global__ void wprep_kernel(const float* __restrict__ wl,
                             unsigned short* __restrict__ wm,
                             unsigned short* __restrict__ wv) {
  int i = blockIdx.x * blockDim.x + threadIdx.x;       // 2 elems each
  f32x4 v = *reinterpret_cast<const f32x4*>(wl + (size_t)i * 4);
  float pm0 = 1.f / (1.f + expf(-v.x));
  float ps0 = 1.f / (1.f + expf(-v.y));
  float pm1 = 1.f / (1.f + expf(-v.z));
  float ps1 = 1.f / (1.f + expf(-v.w));
  float m0 = pm0 * (2.f * ps0 - 1.f);
  float m1 = pm1 * (2.f * ps1 - 1.f);
  float q0 = pm0 - m0 * m0;
  float q1 = pm1 - m1 * m1;
  us2 am = {f2bf(m0), f2bf(m1)};
  us2 av = {f2bf(q0), f2bf(q1)};
  *reinterpret_cast<us2*>(wm + (size_t)i * 2) = am;
  *reinterpret_cast<us2*>(wv + (size_t)i * 2) = av;
}

// ---------------------------------------------------------------------------
// Prep 2: x f32 -> bf16 x (and bf16 x^2 when SQ), row-major same layout.
// ---------------------------------------------------------------------------
template <bool SQ>
__global__ void xprep_kernel(const float* __restrict__ x,
                             unsigned short* __restrict__ xbf,
                             unsigned short* __restrict__ xbf2) {
  const int t = blockIdx.x * blockDim.x + threadIdx.x;
#pragma unroll
  for (int i = 0; i < 4; ++i) {
    size_t c = (size_t)i * 1048576 + t;
    const float* s = x + c * 8;
    f32x4 v0 = *reinterpret_cast<const f32x4*>(s);
    f32x4 v1 = *reinterpret_cast<const f32x4*>(s + 4);
    us8 o = {bfc(v0.x), bfc(v0.y), bfc(v0.z), bfc(v0.w),
             bfc(v1.x), bfc(v1.y), bfc(v1.z), bfc(v1.w)};
    *reinterpret_cast<us8*>(xbf + c * 8) = o;
    if constexpr (SQ) {
      us8 o2 = {bfc(v0.x * v0.x), bfc(v0.y * v0.y), bfc(v0.z * v0.z),
                bfc(v0.w * v0.w), bfc(v1.x * v1.x), bfc(v1.y * v1.y),
                bfc(v1.z * v1.z), bfc(v1.w * v1.w)};
      *reinterpret_cast<us8*>(xbf2 + c * 8) = o2;
    }
  }
}

// ---------------------------------------------------------------------------
// Dual GEMM + fused epilogue.
// Per-buffer LDS (PRE=2): AsX@0 | AsX2@8K | BsM@16K | BsV@24K   (32KB)
//              (PRE<2):  AsX@0 | BsM@8K  | BsV@16K             (24KB)
// Each tile [128][32] bf16 in paired-row layout (see header).
// ---------------------------------------------------------------------------
template <int PRE>
__global__ __launch_bounds__(THREADS, 4) void ternary_gemm(
    const float* __restrict__ x,
    const unsigned short* __restrict__ xbf,
    const unsigned short* __restrict__ xbf2,
    const unsigned short* __restrict__ wm,
    const unsigned short* __restrict__ wv,
    const float* __restrict__ scale,
    const float* __restrict__ shift,
    const float* __restrict__ noise,
    float* __restrict__ out) {
  constexpr int BUFSZ = (PRE == 2) ? 32768 : 24576;
  constexpr int BOFF  = (PRE == 2) ? 16384 : 8192;
  __shared__ alignas(16) char smem[2 * BUFSZ];

  const int tid  = threadIdx.x;
  const int lane = tid & 63;
  const int w    = tid >> 6;       // 0..7
  const bool isVar = (w >= 4);
  const int p    = w & 3;          // region id (2x2 grid of 64x64)
  const int wr   = p >> 1;
  const int wc   = p & 1;
  const int l15  = lane & 15;
  const int l4   = lane >> 4;

  // XCD-bijective swizzle (2048 blocks % 8 == 0), bn-inner per XCD
  const int bid = blockIdx.x;
  const int swz = (bid & 7) * 256 + (bid >> 3);
  const int bm  = swz >> 3;        // 0..255
  const int bn  = swz & 7;         // 0..7
  const int rowBase = bm * BM;
  const int colBase = bn * BN;

  f32x4 acc[4][4];
#pragma unroll
  for (int i = 0; i < 4; ++i)
#pragma unroll
    for (int j = 0; j < 4; ++j) acc[i][j] = (f32x4)0.f;

  // ---- staging geometry (paired-row layout, inverse-swizzled source) ------
  const int lr    = tid >> 3;              // LDS row 0..63
  const int sslot = tid & 7;
  const int lslot = sslot ^ (lr & 7);
  const int r_    = lr * 2 + (lslot >> 2); // matrix row 0..127
  const int ke    = (lslot & 3) * 8;       // element offset in k
  const size_t gB = (size_t)(colBase + r_) * KDIM + ke;  // + k0
  const size_t gA = (size_t)(rowBase + r_) * KDIM + ke;

  auto stage = [&](int kt, char* buf) {
    const int k0 = kt * BK;
    gl_lds16(wm + gB + k0, buf + BOFF + tid * 16);
    gl_lds16(wv + gB + k0, buf + BOFF + 8192 + tid * 16);
    if constexpr (PRE >= 1) {
      gl_lds16(xbf + gA + k0, buf + tid * 16);
      if constexpr (PRE == 2)
        gl_lds16(xbf2 + gA + k0, buf + 8192 + tid * 16);
    } else {
      const float* s = x + gA + k0;
      f32x4 v0 = *reinterpret_cast<const f32x4*>(s);
      f32x4 v1 = *reinterpret_cast<const f32x4*>(s + 4);
      us8 o = {bfc(v0.x), bfc(v0.y), bfc(v0.z), bfc(v0.w),
               bfc(v1.x), bfc(v1.y), bfc(v1.z), bfc(v1.w)};
      *reinterpret_cast<us8*>(buf + tid * 16) = o;   // linear physical chunk
    }
  };

  // read-side byte offset for matrix row `row`, k-chunk l4 (16B)
  auto lbyte = [&](int row) {
    int lrr  = row >> 1;
    int slot = (((row & 1) << 2) | l4) ^ (lrr & 7);
    return lrr * 128 + slot * 16;
  };

  // ---- prologue
  stage(0, smem);
  __syncthreads();

  // ---- main loop: one barrier per k-tile, dbuf hides DMA latency
  for (int kt = 0; kt < NKT; ++kt) {
    const char* cur = smem + (size_t)(kt & 1) * BUFSZ;
    if (kt + 1 < NKT)
      stage(kt + 1, smem + (size_t)((kt + 1) & 1) * BUFSZ);

    const char* Ab = cur + ((PRE == 2 && isVar) ? 8192 : 0);
    const char* Bb = cur + BOFF + (isVar ? 8192 : 0);
    us8 bfr[4], afr[4];
#pragma unroll
    for (int b = 0; b < 4; ++b)
      bfr[b] = *reinterpret_cast<const us8*>(Bb + lbyte(wc * 64 + b * 16 + l15));
#pragma unroll
    for (int a = 0; a < 4; ++a) {
      afr[a] = *reinterpret_cast<const us8*>(Ab + lbyte(wr * 64 + a * 16 + l15));
      if (PRE != 2 && isVar) afr[a] = sqr8(afr[a]);
    }
    __builtin_amdgcn_s_setprio(1);
#pragma unroll
    for (int a = 0; a < 4; ++a)
#pragma unroll
      for (int b = 0; b < 4; ++b)
        acc[a][b] = mfma16(afr[a], bfr[b], acc[a][b]);
    __builtin_amdgcn_s_setprio(0);

    __syncthreads();   // drains next-tile DMA (had full compute phase to land)
  }

  // ---- epilogue: bf16 cross-wave exchange (32KB), XOR'd 2-way (free).
  // mean wave p ships M rows 32..63 of its region; var ships V rows 0..31.
  unsigned short* MxB = (unsigned short*)smem;            // [4][32][64]
  unsigned short* VxB = (unsigned short*)(smem + 16384);  // [4][32][64]
  if (!isVar) {
#pragma unroll
    for (int i = 2; i < 4; ++i)
#pragma unroll
      for (int b = 0; b < 4; ++b)
#pragma unroll
        for (int j = 0; j < 4; ++j) {
          int lrx = (i - 2) * 16 + l4 * 4 + j;   // 0..31
          int lc = b * 16 + l15;
          MxB[(p * 32 + lrx) * 64 + (lc ^ (((lrx >> 2) & 3) << 4))] = bfc(acc[i][b][j]);
        }
  } else {
#pragma unroll
    for (int i = 0; i < 2; ++i)
#pragma unroll
      for (int b = 0; b < 4; ++b)
#pragma unroll
        for (int j = 0; j < 4; ++j) {
          int lrx = i * 16 + l4 * 4 + j;         // 0..31
          int lc = b * 16 + l15;
          VxB[(p * 32 + lrx) * 64 + (lc ^ (((lrx >> 2) & 3) << 4))] = bfc(acc[i][b][j]);
        }
  }
  __syncthreads();

  if (!isVar) {
    // finish region rows 0..31: M in regs, V from VxB
#pragma unroll
    for (int i = 0; i < 2; ++i)
#pragma unroll
      for (int b = 0; b < 4; ++b) {
        int col = colBase + wc * 64 + b * 16 + l15;
        float sc = scale[col], sh = shift[col];
#pragma unroll
        for (int j = 0; j < 4; ++j) {
          int lrx = i * 16 + l4 * 4 + j;
          int lc = b * 16 + l15;
          float vv = bf2f(VxB[(p * 32 + lrx) * 64 + (lc ^ (((lrx >> 2) & 3) << 4))]);
          size_t idx = (size_t)(rowBase + wr * 64 + lrx) * ODIM + col;
          out[idx] = fmaf(acc[i][b][j] + sqrtf(fmaxf(vv, 0.f)) * noise[idx], sc, sh);
        }
      }
  } else {
    // finish region rows 32..63: V in regs, M from MxB
#pragma unroll
    for (int i = 2; i < 4; ++i)
#pragma unroll
      for (int b = 0; b < 4; ++b) {
        int col = colBase + wc * 64 + b * 16 + l15;
        float sc = scale[col], sh = shift[col];
#pragma unroll
        for (int j = 0; j < 4; ++j) {
          int lrx = (i - 2) * 16 + l4 * 4 + j;
          int lc = b * 16 + l15;
          float mm = bf2f(MxB[(p * 32 + lrx) * 64 + (lc ^ (((lrx >> 2) & 3) << 4))]);
          size_t idx = (size_t)(rowBase + wr * 64 + 32 + lrx) * ODIM + col;
          out[idx] = fmaf(mm + sqrtf(fmaxf(acc[i][b][j], 0.f)) * noise[idx], sc, sh);
        }
      }
  }
}

// ---------------------------------------------------------------------------
extern "C" void kernel_launch(void* const* d_in, const int* in_sizes, int n_in,
                              void* d_out, int out_size, void* d_ws, size_t ws_size,
                              hipStream_t stream) {
  const float* x     = (const float*)d_in[0];   // [32768,1024]
  const float* wl    = (const float*)d_in[1];   // [1024,1024,2]
  const float* scale = (const float*)d_in[2];   // [1024]
  const float* shift = (const float*)d_in[3];   // [1024]
  const float* noise = (const float*)d_in[4];   // [32768,1024]
  float* out = (float*)d_out;

  unsigned short* wm   = (unsigned short*)d_ws;           // 2 MB
  unsigned short* wv   = wm + (size_t)ODIM * KDIM;        // 2 MB
  unsigned short* xbf  = wv + (size_t)ODIM * KDIM;        // 64 MB
  unsigned short* xbf2 = xbf + (size_t)N_TOK * KDIM;      // 64 MB

  const size_t needW = 2ull * ODIM * KDIM * 2;
  const size_t needX = (size_t)N_TOK * KDIM * 2;
  const int mode = (ws_size >= needW + 2 * needX) ? 2
                 : (ws_size >= needW + needX)     ? 1 : 0;

  wprep_kernel<<<(ODIM * KDIM / 2) / 256, 256, 0, stream>>>(wl, wm, wv);
  if (mode == 2)
    xprep_kernel<true><<<4096, 256, 0, stream>>>(x, xbf, xbf2);
  else if (mode == 1)
    xprep_kernel<false><<<4096, 256, 0, stream>>>(x, xbf, xbf2);

  // grid = (32768/128) * (1024/128) = 2048 blocks of 512 threads
  if (mode == 2)
    ternary_gemm<2><<<2048, THREADS, 0, stream>>>(
        x, xbf, xbf2, wm, wv, scale, shift, noise, out);
  else if (mode == 1)
    ternary_gemm<1><<<2048, THREADS, 0, stream>>>(
        x, xbf, xbf2, wm, wv, scale, shift, noise, out);
  else
    ternary_gemm<0><<<2048, THREADS, 0, stream>>>(
        x, xbf, xbf2, wm, wv, scale, shift, noise, out);
}

// Round 11
// 242.120 us; speedup vs baseline: 1.0966x; 1.0966x over previous
//
#include <hip/hip_runtime.h>
#include <hip/hip_bf16.h>
#include <cmath>

// Problem constants (from reference)
#define N_TOK 32768
#define KDIM  1024
#define ODIM  1024

// GEMM tile: 128x128 block, BK=32, 8 waves duty-split:
//   waves 0-3: mean GEMM (A = x bf16), waves 4-7: var GEMM (sqr8 in-register)
// LDS: double-buffered {AsX 8K | BsM 8K | BsV 8K} = 2 x 24KB = 48KB.
// REGISTER LAW (R7): acc = 64 AGPR -> VGPR <= 64 for 16 waves/CU.
// PAIRED-ROW LAYOUT (R8/R9): [128][32] tile as 64 LDS rows x 128B;
//   row r -> LDS row r>>1, slot ((r&1)<<2|kchunk) ^ (ldsrow&7). 0 conflicts.
// COUNTED-VMCNT LOOP (R11, from R10 lesson): __syncthreads drains vmcnt(0)
//   and exposes the whole DMA latency every tile. Replace with:
//     stage(kt+1) ; vmcnt(3) ; s_barrier   <- DMA(kt) landed block-wide,
//                                             DMA(kt+1) stays IN FLIGHT
//     compute(kt)
//     s_barrier                            <- reader-release of cur before
//                                             iter kt+1 DMAs into it
//   Hazards: (a) compute(kt) reads buf written by DMA(kt): vmcnt(3) waits
//   my wave's 3 oldest loads (= tile kt), barrier extends to all waves.
//   (b) stage(kt+1) overwrites the buffer compute(kt-1) read: trailing
//   barrier of iter kt-1 precedes stage(kt+1) in program order.
//   Barrier counts are uniform (kt+1<NKT is wave-uniform). Last iter: vmcnt(0).
#define BM 128
#define BN 128
#define BK 32
#define NKT (KDIM / BK)   // 32 k-tiles
#define THREADS 512
#define BUFSZ 24576       // 3 x 8KB tiles

typedef float          f32x4  __attribute__((ext_vector_type(4)));
typedef __bf16         bf16x8 __attribute__((ext_vector_type(8)));
typedef unsigned short us8    __attribute__((ext_vector_type(8)));
typedef unsigned short us2    __attribute__((ext_vector_type(2)));

#define VMCNT(n)  asm volatile("s_waitcnt vmcnt(" #n ")" ::: "memory")
#define SBAR()    asm volatile("s_barrier" ::: "memory")
#define SCHED0()  __builtin_amdgcn_sched_barrier(0)

// round-to-nearest-even f32 -> bf16
static __device__ __forceinline__ unsigned short f2bf(float f) {
  unsigned u = __builtin_bit_cast(unsigned, f);
  u += 0x7FFFu + ((u >> 16) & 1u);
  return (unsigned short)(u >> 16);
}
static __device__ __forceinline__ unsigned short bfc(float f) {
  return __builtin_bit_cast(unsigned short, (__bf16)f);
}
static __device__ __forceinline__ float bf2f(unsigned short u) {
  return __builtin_bit_cast(float, (unsigned)u << 16);
}

static __device__ __forceinline__ f32x4 mfma16(us8 a, us8 b, f32x4 c) {
  return __builtin_amdgcn_mfma_f32_16x16x32_bf16(
      __builtin_bit_cast(bf16x8, a), __builtin_bit_cast(bf16x8, b), c, 0, 0, 0);
}

static __device__ __forceinline__ void gl_lds16(const void* g, void* l) {
  __builtin_amdgcn_global_load_lds(
      (const __attribute__((address_space(1))) void*)g,
      (__attribute__((address_space(3))) void*)l, 16, 0, 0);
}

// elementwise square of 8 bf16 (f32 product, RNE repack) — var waves
static __device__ __forceinline__ us8 sqr8(us8 a) {
  us8 r;
#pragma unroll
  for (int i = 0; i < 8; ++i) {
    float f = bf2f(a[i]);
    r[i] = bfc(f * f);
  }
  return r;
}

// ---------------------------------------------------------------------------
// Prep 1: weight_logits [O][I][2] -> bf16 W_mean, W_var
// ---------------------------------------------------------------------------
__global__ void wprep_kernel(const float* __restrict__ wl,
                             unsigned short* __restrict__ wm,
                             unsigned short* __restrict__ wv) {
  int i = blockIdx.x * blockDim.x + threadIdx.x;       // 2 elems each
  f32x4 v = *reinterpret_cast<const f32x4*>(wl + (size_t)i * 4);
  float pm0 = 1.f / (1.f + expf(-v.x));
  float ps0 = 1.f / (1.f + expf(-v.y));
  float pm1 = 1.f / (1.f + expf(-v.z));
  float ps1 = 1.f / (1.f + expf(-v.w));
  float m0 = pm0 * (2.f * ps0 - 1.f);
  float m1 = pm1 * (2.f * ps1 - 1.f);
  float q0 = pm0 - m0 * m0;
  float q1 = pm1 - m1 * m1;
  us2 am = {f2bf(m0), f2bf(m1)};
  us2 av = {f2bf(q0), f2bf(q1)};
  *reinterpret_cast<us2*>(wm + (size_t)i * 2) = am;
  *reinterpret_cast<us2*>(wv + (size_t)i * 2) = av;
}

// ---------------------------------------------------------------------------
// Prep 2: x f32 -> bf16 x, row-major same layout.
// ---------------------------------------------------------------------------
__global__ void xprep_kernel(const float* __restrict__ x,
                             unsigned short* __restrict__ xbf) {
  const int t = blockIdx.x * blockDim.x + threadIdx.x;
#pragma unroll
  for (int i = 0; i < 4; ++i) {
    size_t c = (size_t)i * 1048576 + t;
    const float* s = x + c * 8;
    f32x4 v0 = *reinterpret_cast<const f32x4*>(s);
    f32x4 v1 = *reinterpret_cast<const f32x4*>(s + 4);
    us8 o = {bfc(v0.x), bfc(v0.y), bfc(v0.z), bfc(v0.w),
             bfc(v1.x), bfc(v1.y), bfc(v1.z), bfc(v1.w)};
    *reinterpret_cast<us8*>(xbf + c * 8) = o;
  }
}

// ---------------------------------------------------------------------------
// Dual GEMM + fused epilogue.
// Per-buffer LDS: AsX@0 | BsM@8K | BsV@16K, each [128][32] bf16 paired-row.
// PRE=1: x pre-converted (all-DMA); PRE=0: in-kernel convert fallback.
// ---------------------------------------------------------------------------
template <int PRE>
__global__ __launch_bounds__(THREADS, 4) void ternary_gemm(
    const float* __restrict__ x,
    const unsigned short* __restrict__ xbf,
    const unsigned short* __restrict__ wm,
    const unsigned short* __restrict__ wv,
    const float* __restrict__ scale,
    const float* __restrict__ shift,
    const float* __restrict__ noise,
    float* __restrict__ out) {
  __shared__ alignas(16) char smem[2 * BUFSZ];

  const int tid  = threadIdx.x;
  const int lane = tid & 63;
  const int w    = tid >> 6;       // 0..7
  const bool isVar = (w >= 4);
  const int p    = w & 3;          // region id (2x2 grid of 64x64)
  const int wr   = p >> 1;
  const int wc   = p & 1;
  const int l15  = lane & 15;
  const int l4   = lane >> 4;

  // XCD-bijective swizzle (2048 blocks % 8 == 0), bn-inner per XCD
  const int bid = blockIdx.x;
  const int swz = (bid & 7) * 256 + (bid >> 3);
  const int bm  = swz >> 3;        // 0..255
  const int bn  = swz & 7;         // 0..7
  const int rowBase = bm * BM;
  const int colBase = bn * BN;

  f32x4 acc[4][4];
#pragma unroll
  for (int i = 0; i < 4; ++i)
#pragma unroll
    for (int j = 0; j < 4; ++j) acc[i][j] = (f32x4)0.f;

  // ---- staging geometry (paired-row layout, inverse-swizzled source) ------
  const int lr    = tid >> 3;              // LDS row 0..63
  const int sslot = tid & 7;
  const int lslot = sslot ^ (lr & 7);
  const int r_    = lr * 2 + (lslot >> 2); // matrix row 0..127
  const int ke    = (lslot & 3) * 8;       // element offset in k
  const size_t gB = (size_t)(colBase + r_) * KDIM + ke;  // + k0
  const size_t gA = (size_t)(rowBase + r_) * KDIM + ke;

  // stage one k-tile (3 gl_lds/thread in PRE=1)
  auto stage = [&](int kt, char* buf) {
    const int k0 = kt * BK;
    gl_lds16(wm + gB + k0, buf + 8192 + tid * 16);
    gl_lds16(wv + gB + k0, buf + 16384 + tid * 16);
    if constexpr (PRE) {
      gl_lds16(xbf + gA + k0, buf + tid * 16);
    } else {
      const float* s = x + gA + k0;
      f32x4 v0 = *reinterpret_cast<const f32x4*>(s);
      f32x4 v1 = *reinterpret_cast<const f32x4*>(s + 4);
      us8 o = {bfc(v0.x), bfc(v0.y), bfc(v0.z), bfc(v0.w),
               bfc(v1.x), bfc(v1.y), bfc(v1.z), bfc(v1.w)};
      *reinterpret_cast<us8*>(buf + tid * 16) = o;   // linear physical chunk
    }
  };

  // read-side byte offset for matrix row `row`, k-chunk l4 (16B)
  auto lbyte = [&](int row) {
    int lrr  = row >> 1;
    int slot = (((row & 1) << 2) | l4) ^ (lrr & 7);
    return lrr * 128 + slot * 16;
  };

  // ---- prologue: issue tile 0 DMA (stays in flight until first vmcnt)
  stage(0, smem);

  // ---- main loop: counted vmcnt + bare barriers (see header derivation)
  for (int kt = 0; kt < NKT; ++kt) {
    const char* cur = smem + (size_t)(kt & 1) * BUFSZ;
    if (kt + 1 < NKT) {
      stage(kt + 1, smem + (size_t)((kt + 1) & 1) * BUFSZ);
      if constexpr (PRE) { VMCNT(3); } else { VMCNT(2); }
    } else {
      VMCNT(0);
    }
    SBAR();            // DMA(kt) landed block-wide; DMA(kt+1) still in flight
    SCHED0();

    const char* Bb = cur + 8192 + (isVar ? 8192 : 0);
    us8 bfr[4], afr[4];
#pragma unroll
    for (int b = 0; b < 4; ++b)
      bfr[b] = *reinterpret_cast<const us8*>(Bb + lbyte(wc * 64 + b * 16 + l15));
#pragma unroll
    for (int a = 0; a < 4; ++a) {
      afr[a] = *reinterpret_cast<const us8*>(cur + lbyte(wr * 64 + a * 16 + l15));
      if (isVar) afr[a] = sqr8(afr[a]);
    }
    __builtin_amdgcn_s_setprio(1);
#pragma unroll
    for (int a = 0; a < 4; ++a)
#pragma unroll
      for (int b = 0; b < 4; ++b)
        acc[a][b] = mfma16(afr[a], bfr[b], acc[a][b]);
    __builtin_amdgcn_s_setprio(0);

    SBAR();            // reader-release: all waves done with cur
  }

  // ---- epilogue: bf16 cross-wave exchange (32KB), XOR'd 2-way (free).
  // (All DMA drained: last iter did VMCNT(0); trailing SBAR synced waves.)
  unsigned short* MxB = (unsigned short*)smem;            // [4][32][64]
  unsigned short* VxB = (unsigned short*)(smem + 16384);  // [4][32][64]
  if (!isVar) {
#pragma unroll
    for (int i = 2; i < 4; ++i)
#pragma unroll
      for (int b = 0; b < 4; ++b)
#pragma unroll
        for (int j = 0; j < 4; ++j) {
          int lrx = (i - 2) * 16 + l4 * 4 + j;   // 0..31
          int lc = b * 16 + l15;
          MxB[(p * 32 + lrx) * 64 + (lc ^ (((lrx >> 2) & 3) << 4))] = bfc(acc[i][b][j]);
        }
  } else {
#pragma unroll
    for (int i = 0; i < 2; ++i)
#pragma unroll
      for (int b = 0; b < 4; ++b)
#pragma unroll
        for (int j = 0; j < 4; ++j) {
          int lrx = i * 16 + l4 * 4 + j;         // 0..31
          int lc = b * 16 + l15;
          VxB[(p * 32 + lrx) * 64 + (lc ^ (((lrx >> 2) & 3) << 4))] = bfc(acc[i][b][j]);
        }
  }
  __syncthreads();

  if (!isVar) {
    // finish region rows 0..31: M in regs, V from VxB
#pragma unroll
    for (int i = 0; i < 2; ++i)
#pragma unroll
      for (int b = 0; b < 4; ++b) {
        int col = colBase + wc * 64 + b * 16 + l15;
        float sc = scale[col], sh = shift[col];
#pragma unroll
        for (int j = 0; j < 4; ++j) {
          int lrx = i * 16 + l4 * 4 + j;
          int lc = b * 16 + l15;
          float vv = bf2f(VxB[(p * 32 + lrx) * 64 + (lc ^ (((lrx >> 2) & 3) << 4))]);
          size_t idx = (size_t)(rowBase + wr * 64 + lrx) * ODIM + col;
          out[idx] = fmaf(acc[i][b][j] + sqrtf(fmaxf(vv, 0.f)) * noise[idx], sc, sh);
        }
      }
  } else {
    // finish region rows 32..63: V in regs, M from MxB
#pragma unroll
    for (int i = 2; i < 4; ++i)
#pragma unroll
      for (int b = 0; b < 4; ++b) {
        int col = colBase + wc * 64 + b * 16 + l15;
        float sc = scale[col], sh = shift[col];
#pragma unroll
        for (int j = 0; j < 4; ++j) {
          int lrx = (i - 2) * 16 + l4 * 4 + j;
          int lc = b * 16 + l15;
          float mm = bf2f(MxB[(p * 32 + lrx) * 64 + (lc ^ (((lrx >> 2) & 3) << 4))]);
          size_t idx = (size_t)(rowBase + wr * 64 + 32 + lrx) * ODIM + col;
          out[idx] = fmaf(mm + sqrtf(fmaxf(acc[i][b][j], 0.f)) * noise[idx], sc, sh);
        }
      }
  }
}

// ---------------------------------------------------------------------------
extern "C" void kernel_launch(void* const* d_in, const int* in_sizes, int n_in,
                              void* d_out, int out_size, void* d_ws, size_t ws_size,
                              hipStream_t stream) {
  const float* x     = (const float*)d_in[0];   // [32768,1024]
  const float* wl    = (const float*)d_in[1];   // [1024,1024,2]
  const float* scale = (const float*)d_in[2];   // [1024]
  const float* shift = (const float*)d_in[3];   // [1024]
  const float* noise = (const float*)d_in[4];   // [32768,1024]
  float* out = (float*)d_out;

  unsigned short* wm  = (unsigned short*)d_ws;           // 2 MB
  unsigned short* wv  = wm + (size_t)ODIM * KDIM;        // 2 MB
  unsigned short* xbf = wv + (size_t)ODIM * KDIM;        // 64 MB

  const size_t need = 2ull * ODIM * KDIM * 2 + (size_t)N_TOK * KDIM * 2;
  const bool pre = (ws_size >= need);

  wprep_kernel<<<(ODIM * KDIM / 2) / 256, 256, 0, stream>>>(wl, wm, wv);
  if (pre)
    xprep_kernel<<<4096, 256, 0, stream>>>(x, xbf);

  // grid = (32768/128) * (1024/128) = 2048 blocks of 512 threads
  if (pre)
    ternary_gemm<1><<<2048, THREADS, 0, stream>>>(
        x, xbf, wm, wv, scale, shift, noise, out);
  else
    ternary_gemm<0><<<2048, THREADS, 0, stream>>>(
        x, xbf, wm, wv, scale, shift, noise, out);
}